// Round 8
// baseline (593.715 us; speedup 1.0000x reference)
//
#include <hip/hip_runtime.h>

#define NBATCH 32
#define NDIM 512

// ---- DPP cross-lane primitives (VALU-speed; no LDS, no barriers) ----

template <int CTRL, int RMASK>
__device__ __forceinline__ float dpp_add(float x) {
  int t = __builtin_amdgcn_update_dpp(0, __float_as_int(x), CTRL, RMASK, 0xf,
                                      false);
  return x + __int_as_float(t);
}

// wave64 inclusive prefix sum
__device__ __forceinline__ float prefix_inc(float x) {
  x = dpp_add<0x111, 0xf>(x);  // row_shr:1
  x = dpp_add<0x112, 0xf>(x);  // row_shr:2
  x = dpp_add<0x114, 0xf>(x);  // row_shr:4
  x = dpp_add<0x118, 0xf>(x);  // row_shr:8
  x = dpp_add<0x142, 0xa>(x);  // row_bcast:15 -> rows 1,3
  x = dpp_add<0x143, 0xc>(x);  // row_bcast:31 -> rows 2,3
  return x;
}

// shift one lane up (lane i gets lane i-1); lane 0 receives `fill`
__device__ __forceinline__ float wave_shr1(float x, float fill) {
  return __int_as_float(__builtin_amdgcn_update_dpp(
      __float_as_int(fill), __float_as_int(x), 0x138 /*wave_shr:1*/, 0xf, 0xf,
      false));
}

// one step of the wave64 inclusive affine-composition scan.
// Compose earlier-then-later: B = A*Be + B ; A = A*Ae. Identity = (1,0).
template <int CTRL, int RMASK>
__device__ __forceinline__ void aff_step(float& A, float& B) {
  float Ae = __int_as_float(__builtin_amdgcn_update_dpp(
      __float_as_int(1.0f), __float_as_int(A), CTRL, RMASK, 0xf, false));
  float Be = __int_as_float(__builtin_amdgcn_update_dpp(
      0, __float_as_int(B), CTRL, RMASK, 0xf, false));
  B = fmaf(A, Be, B);
  A = A * Ae;
}

// One wave per batch element; lane i owns columns [8i, 8i+8).
// Algorithm identical to the previous round (linear guess -> true-branch
// sweep recording slopes -> wave affine-composition scan -> final sweep;
// distance-2 register prefetch). NEW: outputs for 8 consecutive rows are
// accumulated in registers and stored once per group, so store-ack latency
// (vmcnt retires in issue order: waiting for a load forces all OLDER vm
// ops, including the previous row's stores, to retire first) is amortized
// 8x instead of paid every row.
__global__ __launch_bounds__(64, 1)
void sb_kernel(const float* __restrict__ x, const float* __restrict__ xm,
               float* __restrict__ out) {
  const int lane = threadIdx.x;
  const size_t base = (size_t)blockIdx.x * NDIM * NDIM + lane * 8;
  const float* xb = x + base;
  const float* mb = xm + base;
  float* ob = out + base;

  float w8[8], fu[8], t8[8];
#pragma unroll
  for (int k = 0; k < 8; ++k) w8[k] = 1.0f;

  // ping-pong load buffers: A holds row 0, B holds row 1
  float4 axA = *(const float4*)(xb);
  float4 axB = *(const float4*)(xb + 4);
  float4 amA = *(const float4*)(mb);
  float4 amB = *(const float4*)(mb + 4);
  float4 bxA = *(const float4*)(xb + NDIM);
  float4 bxB = *(const float4*)(xb + NDIM + 4);
  float4 bmA = *(const float4*)(mb + NDIM);
  float4 bmB = *(const float4*)(mb + NDIM + 4);

  float c1c[8], c2c[8], oc2[8];
  {  // row-0 constants + row-0 scan inputs (w == 1)
    float xr[8] = {axA.x, axA.y, axA.z, axA.w, axB.x, axB.y, axB.z, axB.w};
    float mr[8] = {amA.x, amA.y, amA.z, amA.w, amB.x, amB.y, amB.z, amB.w};
#pragma unroll
    for (int k = 0; k < 8; ++k) {
      float bb = __builtin_amdgcn_rcpf(1.0f + __expf(-xr[k]));
      c2c[k] = mr[k] * bb;
      c1c[k] = mr[k] - c2c[k];
      oc2[k] = 1.0f - c2c[k];
      fu[k] = fmaxf(mr[k], 0.0f);
      t8[k] = c2c[k];
    }
  }

  // wb*: buffer to overwrite with row m+2; rb*: buffer holding row m+1.
  // Fills pv[] instead of storing (stores batched by the caller).
  auto row_body = [&](int m, float4& wxA, float4& wxB, float4& wmA, float4& wmB,
                      const float4& rxA, const float4& rxB, const float4& rmA,
                      const float4& rmB, float (&pv)[8]) {
    // issue row m+2 loads (clamped on the last two iters; results unused)
    const int nr = (m + 2 < NDIM) ? m + 2 : NDIM - 1;
    const size_t nro = (size_t)nr * NDIM;
    wxA = *(const float4*)(xb + nro);
    wxB = *(const float4*)(xb + nro + 4);
    wmA = *(const float4*)(mb + nro);
    wmB = *(const float4*)(mb + nro + 4);

    // ---- scans (fu/t8 were produced by the previous iteration's tail) ----
    float S = ((fu[0] + fu[1]) + (fu[2] + fu[3])) +
              ((fu[4] + fu[5]) + (fu[6] + fu[7]));
    float sa = ((t8[0] + t8[1]) + (t8[2] + t8[3])) +
               ((t8[4] + t8[5]) + (t8[6] + t8[7]));
    float PS = prefix_inc(S);
    float PA = prefix_inc(sa);
    float T = __int_as_float(__builtin_amdgcn_readlane(__float_as_int(PS), 63));
    float R = T - PS;  // future mass strictly after this lane

    // tree-structured within-lane suffix for mfm
    float s23 = fu[2] + fu[3], s45 = fu[4] + fu[5], s67 = fu[6] + fu[7];
    float s4567 = s45 + s67;
    float mfm[8], nc1m[8];
    mfm[7] = R;
    mfm[6] = R + fu[7];
    mfm[5] = R + s67;
    mfm[4] = mfm[5] + fu[5];
    mfm[3] = R + s4567;
    mfm[2] = mfm[3] + fu[3];
    mfm[1] = mfm[3] + s23;
    mfm[0] = mfm[1] + fu[1];
#pragma unroll
    for (int k = 0; k < 8; ++k) nc1m[k] = -c1c[k] * mfm[k];

    const float uin = fmaxf(1.0f - (PA - sa), 0.0f);  // linear guess

    // ---- sweep 1: true branches from uin, record slopes ----
    float u = uin;
    float aa[8];
#pragma unroll
    for (int k = 0; k < 8; ++k) {
      float gf = fmaf(c1c[k], u, nc1m[k]);
      float g = fmaxf(gf, 0.0f);
      float U = fminf(u, w8[k]);
      float a = (w8[k] < u) ? 1.0f : oc2[k];
      a = (gf > 0.0f) ? (a - c1c[k]) : a;
      aa[k] = a;
      u = fmaf(-c2c[k], U, u) - g;
    }
    float A = ((aa[0] * aa[1]) * (aa[2] * aa[3])) *
              ((aa[4] * aa[5]) * (aa[6] * aa[7]));
    float Bv = fmaf(-A, uin, u);  // lane map M(v) = A*v + Bv

    // ---- affine-composition scan + exclusive entry ----
    aff_step<0x111, 0xf>(A, Bv);
    aff_step<0x112, 0xf>(A, Bv);
    aff_step<0x114, 0xf>(A, Bv);
    aff_step<0x118, 0xf>(A, Bv);
    aff_step<0x142, 0xa>(A, Bv);
    aff_step<0x143, 0xc>(A, Bv);
    float Aex = wave_shr1(A, 1.0f);
    float Bex = wave_shr1(Bv, 0.0f);
    float e = fminf(fmaxf(Aex + Bex, 0.0f), 1.0f);  // entry, clamped

    // ---- row m+1 x-only prep (loaded a full iteration ago) ----
    float c1n[8], c2n[8], oc2n[8], omn[8];
    {
      float xr[8] = {rxA.x, rxA.y, rxA.z, rxA.w, rxB.x, rxB.y, rxB.z, rxB.w};
      float mr[8] = {rmA.x, rmA.y, rmA.z, rmA.w, rmB.x, rmB.y, rmB.z, rmB.w};
#pragma unroll
      for (int k = 0; k < 8; ++k) {
        float bb = __builtin_amdgcn_rcpf(1.0f + __expf(-xr[k]));
        c2n[k] = mr[k] * bb;
        c1n[k] = mr[k] - c2n[k];
        oc2n[k] = 1.0f - c2n[k];
        omn[k] = 1.0f - mr[k];
      }
    }

    // ---- final sweep: emit p, update w, build next row's scan inputs ----
    u = e;
#pragma unroll
    for (int k = 0; k < 8; ++k) {
      float g = fmaxf(fmaf(c1c[k], u, nc1m[k]), 0.0f);
      float U = fminf(u, w8[k]);
      float un = fmaf(-c2c[k], U, u) - g;
      float p = u - un;  // off the u-chain
      pv[k] = p;
      float wn = w8[k] - p;
      w8[k] = wn;
      fu[k] = fmaxf(wn - omn[k], 0.0f);
      t8[k] = c2n[k] * wn;
      u = un;
    }

#pragma unroll
    for (int k = 0; k < 8; ++k) {
      c1c[k] = c1n[k];
      c2c[k] = c2n[k];
      oc2[k] = oc2n[k];
    }
  };

#pragma unroll 1
  for (int g = 0; g < NDIM / 8; ++g) {
    float po[8][8];  // 8 rows of output, kept in registers
#pragma unroll
    for (int r = 0; r < 8; r += 2) {
      row_body(g * 8 + r, axA, axB, amA, amB, bxA, bxB, bmA, bmB, po[r]);
      row_body(g * 8 + r + 1, bxA, bxB, bmA, bmB, axA, axB, amA, amB,
               po[r + 1]);
    }
    // batched stores: issued newest in vm order, so the next group's
    // load-waits retire without draining them
    float* orow = ob + (size_t)g * 8 * NDIM;
#pragma unroll
    for (int r = 0; r < 8; ++r) {
      *(float4*)(orow + (size_t)r * NDIM) =
          make_float4(po[r][0], po[r][1], po[r][2], po[r][3]);
      *(float4*)(orow + (size_t)r * NDIM + 4) =
          make_float4(po[r][4], po[r][5], po[r][6], po[r][7]);
    }
  }
}

extern "C" void kernel_launch(void* const* d_in, const int* in_sizes, int n_in,
                              void* d_out, int out_size, void* d_ws, size_t ws_size,
                              hipStream_t stream) {
  const float* x = (const float*)d_in[0];
  const float* xmask = (const float*)d_in[1];
  float* out = (float*)d_out;
  (void)in_sizes; (void)n_in; (void)out_size; (void)d_ws; (void)ws_size;
  hipLaunchKernelGGL(sb_kernel, dim3(NBATCH), dim3(64), 0, stream, x, xmask, out);
}

// Round 9
// 453.332 us; speedup vs baseline: 1.3097x; 1.3097x over previous
//
#include <hip/hip_runtime.h>

#define NBATCH 32
#define NDIM 512

// ---- DPP cross-lane primitives (VALU-speed; no LDS, no barriers) ----

template <int CTRL, int RMASK>
__device__ __forceinline__ float dpp_add(float x) {
  int t = __builtin_amdgcn_update_dpp(0, __float_as_int(x), CTRL, RMASK, 0xf,
                                      false);
  return x + __int_as_float(t);
}

// wave64 inclusive prefix sum
__device__ __forceinline__ float prefix_inc(float x) {
  x = dpp_add<0x111, 0xf>(x);  // row_shr:1
  x = dpp_add<0x112, 0xf>(x);  // row_shr:2
  x = dpp_add<0x114, 0xf>(x);  // row_shr:4
  x = dpp_add<0x118, 0xf>(x);  // row_shr:8
  x = dpp_add<0x142, 0xa>(x);  // row_bcast:15 -> rows 1,3
  x = dpp_add<0x143, 0xc>(x);  // row_bcast:31 -> rows 2,3
  return x;
}

// shift one lane up (lane i gets lane i-1); lane 0 receives `fill`
__device__ __forceinline__ float wave_shr1(float x, float fill) {
  return __int_as_float(__builtin_amdgcn_update_dpp(
      __float_as_int(fill), __float_as_int(x), 0x138 /*wave_shr:1*/, 0xf, 0xf,
      false));
}

// one step of the wave64 inclusive affine-composition scan.
// Compose earlier-then-later: B = A*Be + B ; A = A*Ae. Identity = (1,0).
template <int CTRL, int RMASK>
__device__ __forceinline__ void aff_step(float& A, float& B) {
  float Ae = __int_as_float(__builtin_amdgcn_update_dpp(
      __float_as_int(1.0f), __float_as_int(A), CTRL, RMASK, 0xf, false));
  float Be = __int_as_float(__builtin_amdgcn_update_dpp(
      0, __float_as_int(B), CTRL, RMASK, 0xf, false));
  B = fmaf(A, Be, B);
  A = A * Ae;
}

// One wave per batch element; lane i owns columns [8i, 8i+8).
// Algorithm identical to R7 (linear guess -> true-branch sweep recording
// slopes -> wave affine-composition scan -> final sweep; per-row stores).
// NEW: DISTANCE-4 register prefetch pipeline (4 row slots, rotated by a
// 4x-unrolled loop). The s_waitcnt for row r's prep data now sits ~3.2
// row-bodies (~1500+ cyc) after the loads were issued -- covering HBM-miss
// latency -- and all recent stores are younger than the awaited loads, so
// fine-grained vmcnt(N) waits retire them without draining the store queue.
__global__ __launch_bounds__(64, 1)
void sb_kernel(const float* __restrict__ x, const float* __restrict__ xm,
               float* __restrict__ out) {
  const int lane = threadIdx.x;
  const size_t base = (size_t)blockIdx.x * NDIM * NDIM + lane * 8;
  const float* xb = x + base;
  const float* mb = xm + base;
  float* ob = out + base;

  float w8[8], fu[8], t8[8];
#pragma unroll
  for (int k = 0; k < 8; ++k) w8[k] = 1.0f;

  // 4 prefetch slots, one row each: {xA,xB}, {mA,mB}
  float4 x0[2], m0[2], x1[2], m1[2], x2[2], m2[2], x3[2], m3[2];
  x0[0] = *(const float4*)(xb);
  x0[1] = *(const float4*)(xb + 4);
  m0[0] = *(const float4*)(mb);
  m0[1] = *(const float4*)(mb + 4);
  x1[0] = *(const float4*)(xb + NDIM);
  x1[1] = *(const float4*)(xb + NDIM + 4);
  m1[0] = *(const float4*)(mb + NDIM);
  m1[1] = *(const float4*)(mb + NDIM + 4);
  x2[0] = *(const float4*)(xb + 2 * NDIM);
  x2[1] = *(const float4*)(xb + 2 * NDIM + 4);
  m2[0] = *(const float4*)(mb + 2 * NDIM);
  m2[1] = *(const float4*)(mb + 2 * NDIM + 4);
  x3[0] = *(const float4*)(xb + 3 * NDIM);
  x3[1] = *(const float4*)(xb + 3 * NDIM + 4);
  m3[0] = *(const float4*)(mb + 3 * NDIM);
  m3[1] = *(const float4*)(mb + 3 * NDIM + 4);

  float c1c[8], c2c[8], oc2[8];
  {  // row-0 constants + row-0 scan inputs (w == 1)
    float xr[8] = {x0[0].x, x0[0].y, x0[0].z, x0[0].w,
                   x0[1].x, x0[1].y, x0[1].z, x0[1].w};
    float mr[8] = {m0[0].x, m0[0].y, m0[0].z, m0[0].w,
                   m0[1].x, m0[1].y, m0[1].z, m0[1].w};
#pragma unroll
    for (int k = 0; k < 8; ++k) {
      float bb = __builtin_amdgcn_rcpf(1.0f + __expf(-xr[k]));
      c2c[k] = mr[k] * bb;
      c1c[k] = mr[k] - c2c[k];
      oc2[k] = 1.0f - c2c[k];
      fu[k] = fmaxf(mr[k], 0.0f);
      t8[k] = c2c[k];
    }
  }

  // W*: slot to overwrite with row m+4 (its row-m data was consumed at the
  // prep in iteration m-1). R*: slot holding row m+1 (loaded at m-3).
  auto row_body = [&](int m, float4 (&WX)[2], float4 (&WM)[2],
                      const float4 (&RX)[2], const float4 (&RM)[2]) {
    const int nr = (m + 4 < NDIM) ? m + 4 : NDIM - 1;
    const size_t nro = (size_t)nr * NDIM;
    WX[0] = *(const float4*)(xb + nro);
    WX[1] = *(const float4*)(xb + nro + 4);
    WM[0] = *(const float4*)(mb + nro);
    WM[1] = *(const float4*)(mb + nro + 4);

    // ---- scans (fu/t8 were produced by the previous iteration's tail) ----
    float S = ((fu[0] + fu[1]) + (fu[2] + fu[3])) +
              ((fu[4] + fu[5]) + (fu[6] + fu[7]));
    float sa = ((t8[0] + t8[1]) + (t8[2] + t8[3])) +
               ((t8[4] + t8[5]) + (t8[6] + t8[7]));
    float PS = prefix_inc(S);
    float PA = prefix_inc(sa);
    float T = __int_as_float(__builtin_amdgcn_readlane(__float_as_int(PS), 63));
    float R = T - PS;  // future mass strictly after this lane

    // tree-structured within-lane suffix for mfm
    float s23 = fu[2] + fu[3], s45 = fu[4] + fu[5], s67 = fu[6] + fu[7];
    float s4567 = s45 + s67;
    float mfm[8], nc1m[8];
    mfm[7] = R;
    mfm[6] = R + fu[7];
    mfm[5] = R + s67;
    mfm[4] = mfm[5] + fu[5];
    mfm[3] = R + s4567;
    mfm[2] = mfm[3] + fu[3];
    mfm[1] = mfm[3] + s23;
    mfm[0] = mfm[1] + fu[1];
#pragma unroll
    for (int k = 0; k < 8; ++k) nc1m[k] = -c1c[k] * mfm[k];

    const float uin = fmaxf(1.0f - (PA - sa), 0.0f);  // linear guess

    // ---- sweep 1: true branches from uin, record slopes ----
    float u = uin;
    float aa[8];
#pragma unroll
    for (int k = 0; k < 8; ++k) {
      float gf = fmaf(c1c[k], u, nc1m[k]);
      float g = fmaxf(gf, 0.0f);
      float U = fminf(u, w8[k]);
      float a = (w8[k] < u) ? 1.0f : oc2[k];
      a = (gf > 0.0f) ? (a - c1c[k]) : a;
      aa[k] = a;
      u = fmaf(-c2c[k], U, u) - g;
    }
    float A = ((aa[0] * aa[1]) * (aa[2] * aa[3])) *
              ((aa[4] * aa[5]) * (aa[6] * aa[7]));
    float Bv = fmaf(-A, uin, u);  // lane map M(v) = A*v + Bv

    // ---- affine-composition scan + exclusive entry ----
    aff_step<0x111, 0xf>(A, Bv);
    aff_step<0x112, 0xf>(A, Bv);
    aff_step<0x114, 0xf>(A, Bv);
    aff_step<0x118, 0xf>(A, Bv);
    aff_step<0x142, 0xa>(A, Bv);
    aff_step<0x143, 0xc>(A, Bv);
    float Aex = wave_shr1(A, 1.0f);
    float Bex = wave_shr1(Bv, 0.0f);
    float e = fminf(fmaxf(Aex + Bex, 0.0f), 1.0f);  // entry, clamped

    // ---- row m+1 x-only prep (data loaded 3+ rows ago; no stall) ----
    float c1n[8], c2n[8], oc2n[8], omn[8];
    {
      float xr[8] = {RX[0].x, RX[0].y, RX[0].z, RX[0].w,
                     RX[1].x, RX[1].y, RX[1].z, RX[1].w};
      float mr[8] = {RM[0].x, RM[0].y, RM[0].z, RM[0].w,
                     RM[1].x, RM[1].y, RM[1].z, RM[1].w};
#pragma unroll
      for (int k = 0; k < 8; ++k) {
        float bb = __builtin_amdgcn_rcpf(1.0f + __expf(-xr[k]));
        c2n[k] = mr[k] * bb;
        c1n[k] = mr[k] - c2n[k];
        oc2n[k] = 1.0f - c2n[k];
        omn[k] = 1.0f - mr[k];
      }
    }

    // ---- final sweep: emit p, update w, build next row's scan inputs ----
    u = e;
    float pv[8];
#pragma unroll
    for (int k = 0; k < 8; ++k) {
      float g = fmaxf(fmaf(c1c[k], u, nc1m[k]), 0.0f);
      float U = fminf(u, w8[k]);
      float un = fmaf(-c2c[k], U, u) - g;
      float p = u - un;  // off the u-chain
      pv[k] = p;
      float wn = w8[k] - p;
      w8[k] = wn;
      fu[k] = fmaxf(wn - omn[k], 0.0f);
      t8[k] = c2n[k] * wn;
      u = un;
    }
    float* orow = ob + (size_t)m * NDIM;
    *(float4*)(orow) = make_float4(pv[0], pv[1], pv[2], pv[3]);
    *(float4*)(orow + 4) = make_float4(pv[4], pv[5], pv[6], pv[7]);

#pragma unroll
    for (int k = 0; k < 8; ++k) {
      c1c[k] = c1n[k];
      c2c[k] = c2n[k];
      oc2[k] = oc2n[k];
    }
  };

#pragma unroll 1
  for (int m = 0; m < NDIM; m += 4) {
    row_body(m + 0, x0, m0, x1, m1);
    row_body(m + 1, x1, m1, x2, m2);
    row_body(m + 2, x2, m2, x3, m3);
    row_body(m + 3, x3, m3, x0, m0);
  }
}

extern "C" void kernel_launch(void* const* d_in, const int* in_sizes, int n_in,
                              void* d_out, int out_size, void* d_ws, size_t ws_size,
                              hipStream_t stream) {
  const float* x = (const float*)d_in[0];
  const float* xmask = (const float*)d_in[1];
  float* out = (float*)d_out;
  (void)in_sizes; (void)n_in; (void)out_size; (void)d_ws; (void)ws_size;
  hipLaunchKernelGGL(sb_kernel, dim3(NBATCH), dim3(64), 0, stream, x, xmask, out);
}

// Round 11
// 409.538 us; speedup vs baseline: 1.4497x; 1.1069x over previous
//
#include <hip/hip_runtime.h>

#define NBATCH 32
#define NDIM 512

// ---- DPP cross-lane primitives (VALU-speed; no LDS, no barriers) ----

template <int CTRL, int RMASK>
__device__ __forceinline__ float dpp_add(float x) {
  int t = __builtin_amdgcn_update_dpp(0, __float_as_int(x), CTRL, RMASK, 0xf,
                                      false);
  return x + __int_as_float(t);
}

// wave64 inclusive prefix sum
__device__ __forceinline__ float prefix_inc(float x) {
  x = dpp_add<0x111, 0xf>(x);  // row_shr:1
  x = dpp_add<0x112, 0xf>(x);  // row_shr:2
  x = dpp_add<0x114, 0xf>(x);  // row_shr:4
  x = dpp_add<0x118, 0xf>(x);  // row_shr:8
  x = dpp_add<0x142, 0xa>(x);  // row_bcast:15 -> rows 1,3
  x = dpp_add<0x143, 0xc>(x);  // row_bcast:31 -> rows 2,3
  return x;
}

// shift one lane up (lane i gets lane i-1); lane 0 receives `fill`
__device__ __forceinline__ float wave_shr1(float x, float fill) {
  return __int_as_float(__builtin_amdgcn_update_dpp(
      __float_as_int(fill), __float_as_int(x), 0x138 /*wave_shr:1*/, 0xf, 0xf,
      false));
}

// one step of the wave64 inclusive affine-composition scan.
// Compose earlier-then-later: B = A*Be + B ; A = A*Ae. Identity = (1,0).
template <int CTRL, int RMASK>
__device__ __forceinline__ void aff_step(float& A, float& B) {
  float Ae = __int_as_float(__builtin_amdgcn_update_dpp(
      __float_as_int(1.0f), __float_as_int(A), CTRL, RMASK, 0xf, false));
  float Be = __int_as_float(__builtin_amdgcn_update_dpp(
      0, __float_as_int(B), CTRL, RMASK, 0xf, false));
  B = fmaf(A, Be, B);
  A = A * Ae;
}

// One wave per batch element; lane i owns columns [8i, 8i+8).
// Branch prediction is from the CURRENT-row linear guess (u_g[k] =
// uin - pre[k], pre = within-lane exclusive prefix of t8=c2*w, built in the
// previous row's tail). This guess is exact up through the frontier column
// and lands on the correct side of both branch comparisons beyond it
// (R10's stale-row predictor was wrong AT the frontier -> 0.8 absmax; this
// one is the R6-R9 predictor made fully parallel). No serial sweeps at all:
// piecewise-affine pieces -> depth-3 composition tree -> wave affine scan
// -> within-lane entries from tree intermediates -> parallel true-branch
// output evaluation. Distance-4 register prefetch kept from R9.
__global__ __launch_bounds__(64, 1)
void sb_kernel(const float* __restrict__ x, const float* __restrict__ xm,
               float* __restrict__ out) {
  const int lane = threadIdx.x;
  const size_t base = (size_t)blockIdx.x * NDIM * NDIM + lane * 8;
  const float* xb = x + base;
  const float* mb = xm + base;
  float* ob = out + base;

  float w8[8], fu[8], t8[8], pre[8], suf[8];
  float S, sa;
  float c1c[8], c2c[8], oc2[8];

  // 4 prefetch slots, one row each
  float4 x0[2], m0[2], x1[2], m1[2], x2[2], m2[2], x3[2], m3[2];
  x0[0] = *(const float4*)(xb);
  x0[1] = *(const float4*)(xb + 4);
  m0[0] = *(const float4*)(mb);
  m0[1] = *(const float4*)(mb + 4);
  x1[0] = *(const float4*)(xb + NDIM);
  x1[1] = *(const float4*)(xb + NDIM + 4);
  m1[0] = *(const float4*)(mb + NDIM);
  m1[1] = *(const float4*)(mb + NDIM + 4);
  x2[0] = *(const float4*)(xb + 2 * NDIM);
  x2[1] = *(const float4*)(xb + 2 * NDIM + 4);
  m2[0] = *(const float4*)(mb + 2 * NDIM);
  m2[1] = *(const float4*)(mb + 2 * NDIM + 4);
  x3[0] = *(const float4*)(xb + 3 * NDIM);
  x3[1] = *(const float4*)(xb + 3 * NDIM + 4);
  m3[0] = *(const float4*)(mb + 3 * NDIM);
  m3[1] = *(const float4*)(mb + 3 * NDIM + 4);

  // tail helper: build pre/suf trees + S/sa from current fu/t8
  auto build_tail = [&]() {
    float q01 = t8[0] + t8[1], q23 = t8[2] + t8[3], q45 = t8[4] + t8[5];
    pre[0] = 0.0f;
    pre[1] = t8[0];
    pre[2] = q01;
    pre[3] = q01 + t8[2];
    pre[4] = q01 + q23;
    pre[5] = pre[4] + t8[4];
    pre[6] = pre[4] + q45;
    pre[7] = pre[6] + t8[6];
    sa = pre[7] + t8[7];
    float r23 = fu[2] + fu[3], r45 = fu[4] + fu[5], r67 = fu[6] + fu[7];
    float r4567 = r45 + r67;
    suf[7] = 0.0f;
    suf[6] = fu[7];
    suf[5] = r67;
    suf[4] = fu[5] + r67;
    suf[3] = r4567;
    suf[2] = fu[3] + r4567;
    suf[1] = r23 + r4567;
    suf[0] = fu[1] + suf[1];
    S = ((fu[0] + fu[1]) + r23) + r4567;
  };

  {  // row-0 prep: constants + scan inputs (w == 1, cs == 0)
    float xr[8] = {x0[0].x, x0[0].y, x0[0].z, x0[0].w,
                   x0[1].x, x0[1].y, x0[1].z, x0[1].w};
    float mr[8] = {m0[0].x, m0[0].y, m0[0].z, m0[0].w,
                   m0[1].x, m0[1].y, m0[1].z, m0[1].w};
#pragma unroll
    for (int k = 0; k < 8; ++k) {
      float bb = __builtin_amdgcn_rcpf(1.0f + __expf(-xr[k]));
      c2c[k] = mr[k] * bb;
      c1c[k] = mr[k] - c2c[k];
      oc2[k] = 1.0f - c2c[k];
      w8[k] = 1.0f;
      fu[k] = mr[k];
      t8[k] = c2c[k];
    }
    build_tail();
  }

  // W*: slot to overwrite with row m+4; R*: slot holding row m+1.
  auto row_body = [&](int m, float4 (&WX)[2], float4 (&WM)[2],
                      const float4 (&RX)[2], const float4 (&RM)[2]) {
    const int nr = (m + 4 < NDIM) ? m + 4 : NDIM - 1;
    const size_t nro = (size_t)nr * NDIM;
    WX[0] = *(const float4*)(xb + nro);
    WX[1] = *(const float4*)(xb + nro + 4);
    WM[0] = *(const float4*)(mb + nro);
    WM[1] = *(const float4*)(mb + nro + 4);

    // ---- chain head: two interleaved DPP prefix scans ----
    float PS = prefix_inc(S);
    float PA = prefix_inc(sa);
    float T = __int_as_float(__builtin_amdgcn_readlane(__float_as_int(PS), 63));
    float R_ = T - PS;                          // future mass after this lane
    float uin = fmaxf(1.0f - (PA - sa), 0.0f);  // linear entry guess

    float mfm[8], nc1m[8];
#pragma unroll
    for (int k = 0; k < 8; ++k) {
      mfm[k] = R_ + suf[k];
      nc1m[k] = -c1c[k] * mfm[k];
    }

    // ---- parallel branch prediction at current-row linear guesses ----
    float aP[8], bP[8];
#pragma unroll
    for (int k = 0; k < 8; ++k) {
      float ug = uin - pre[k];
      bool pW = w8[k] < ug;    // U = w  (else U = u)
      bool pL = ug > mfm[k];   // L-branch active
      float a = pW ? 1.0f : oc2[k];
      aP[k] = pL ? (a - c1c[k]) : a;
      float b0 = pW ? (-t8[k]) : 0.0f;  // -c2*w
      bP[k] = pL ? (b0 - nc1m[k]) : b0;  // + c1*mfm
    }

    // ---- depth-3 composition tree (intermediates reused below) ----
    float a01 = aP[1] * aP[0], b01 = fmaf(aP[1], bP[0], bP[1]);
    float a23 = aP[3] * aP[2], b23 = fmaf(aP[3], bP[2], bP[3]);
    float a45 = aP[5] * aP[4], b45 = fmaf(aP[5], bP[4], bP[5]);
    float a67 = aP[7] * aP[6], b67 = fmaf(aP[7], bP[6], bP[7]);
    float a03 = a23 * a01, b03 = fmaf(a23, b01, b23);
    float a47 = a67 * a45, b47 = fmaf(a67, b45, b67);
    float A = a47 * a03, Bv = fmaf(a47, b03, b47);

    // ---- affine-composition wave scan + exclusive entry ----
    aff_step<0x111, 0xf>(A, Bv);
    aff_step<0x112, 0xf>(A, Bv);
    aff_step<0x114, 0xf>(A, Bv);
    aff_step<0x118, 0xf>(A, Bv);
    aff_step<0x142, 0xa>(A, Bv);
    aff_step<0x143, 0xc>(A, Bv);
    float Aex = wave_shr1(A, 1.0f);
    float Bex = wave_shr1(Bv, 0.0f);
    float e = fminf(fmaxf(Aex + Bex, 0.0f), 1.0f);

    // ---- row m+1 x-only prep (data loaded 3+ rows ago; off-chain) ----
    float c1n[8], c2n[8], oc2n[8], omn[8];
    {
      float xr[8] = {RX[0].x, RX[0].y, RX[0].z, RX[0].w,
                     RX[1].x, RX[1].y, RX[1].z, RX[1].w};
      float mr[8] = {RM[0].x, RM[0].y, RM[0].z, RM[0].w,
                     RM[1].x, RM[1].y, RM[1].z, RM[1].w};
#pragma unroll
      for (int k = 0; k < 8; ++k) {
        float bb = __builtin_amdgcn_rcpf(1.0f + __expf(-xr[k]));
        c2n[k] = mr[k] * bb;
        c1n[k] = mr[k] - c2n[k];
        oc2n[k] = 1.0f - c2n[k];
        omn[k] = 1.0f - mr[k];
      }
    }

    // ---- within-lane entries from composition-tree intermediates ----
    float uu[8];
    uu[0] = e;
    uu[1] = fmaf(aP[0], e, bP[0]);
    uu[2] = fmaf(a01, e, b01);
    uu[4] = fmaf(a03, e, b03);
    uu[3] = fmaf(aP[2], uu[2], bP[2]);
    uu[6] = fmaf(a45, uu[4], b45);
    uu[5] = fmaf(aP[4], uu[4], bP[4]);
    uu[7] = fmaf(aP[6], uu[6], bP[6]);
#pragma unroll
    for (int k = 0; k < 8; ++k) uu[k] = fmaxf(uu[k], 0.0f);

    // ---- TRUE-branch outputs, all columns in parallel ----
    float pv[8];
#pragma unroll
    for (int k = 0; k < 8; ++k) {
      float g = fmaxf(fmaf(c1c[k], uu[k], nc1m[k]), 0.0f);  // c1*max(u-mfm,0)
      float U = fminf(uu[k], w8[k]);
      float p = fmaf(c2c[k], U, g);
      pv[k] = p;
      w8[k] -= p;
    }
    float* orow = ob + (size_t)m * NDIM;
    *(float4*)(orow) = make_float4(pv[0], pv[1], pv[2], pv[3]);
    *(float4*)(orow + 4) = make_float4(pv[4], pv[5], pv[6], pv[7]);

    // ---- next row's scan inputs + trees (the real cross-row chain) ----
#pragma unroll
    for (int k = 0; k < 8; ++k) {
      fu[k] = fmaxf(w8[k] - omn[k], 0.0f);
      t8[k] = c2n[k] * w8[k];
    }
    build_tail();

#pragma unroll
    for (int k = 0; k < 8; ++k) {
      c1c[k] = c1n[k];
      c2c[k] = c2n[k];
      oc2[k] = oc2n[k];
    }
  };

#pragma unroll 1
  for (int m = 0; m < NDIM; m += 4) {
    row_body(m + 0, x0, m0, x1, m1);
    row_body(m + 1, x1, m1, x2, m2);
    row_body(m + 2, x2, m2, x3, m3);
    row_body(m + 3, x3, m3, x0, m0);
  }
}

extern "C" void kernel_launch(void* const* d_in, const int* in_sizes, int n_in,
                              void* d_out, int out_size, void* d_ws, size_t ws_size,
                              hipStream_t stream) {
  const float* x = (const float*)d_in[0];
  const float* xmask = (const float*)d_in[1];
  float* out = (float*)d_out;
  (void)in_sizes; (void)n_in; (void)out_size; (void)d_ws; (void)ws_size;
  hipLaunchKernelGGL(sb_kernel, dim3(NBATCH), dim3(64), 0, stream, x, xmask, out);
}

// Round 12
// 352.533 us; speedup vs baseline: 1.6841x; 1.1617x over previous
//
#include <hip/hip_runtime.h>
#include <type_traits>

#define NBATCH 32
#define NDIM 512

// ---- DPP cross-lane primitives (VALU-speed; no LDS, no barriers) ----

template <int CTRL, int RMASK>
__device__ __forceinline__ float dpp_add(float x) {
  int t = __builtin_amdgcn_update_dpp(0, __float_as_int(x), CTRL, RMASK, 0xf,
                                      false);
  return x + __int_as_float(t);
}

// wave64 inclusive prefix sum
__device__ __forceinline__ float prefix_inc(float x) {
  x = dpp_add<0x111, 0xf>(x);  // row_shr:1
  x = dpp_add<0x112, 0xf>(x);  // row_shr:2
  x = dpp_add<0x114, 0xf>(x);  // row_shr:4
  x = dpp_add<0x118, 0xf>(x);  // row_shr:8
  x = dpp_add<0x142, 0xa>(x);  // row_bcast:15 -> rows 1,3
  x = dpp_add<0x143, 0xc>(x);  // row_bcast:31 -> rows 2,3
  return x;
}

// shift one lane up (lane i gets lane i-1); lane 0 receives `fill`
__device__ __forceinline__ float wave_shr1(float x, float fill) {
  return __int_as_float(__builtin_amdgcn_update_dpp(
      __float_as_int(fill), __float_as_int(x), 0x138 /*wave_shr:1*/, 0xf, 0xf,
      false));
}

// one step of the wave64 inclusive affine-composition scan.
// Compose earlier-then-later: B = A*Be + B ; A = A*Ae. Identity = (1,0).
template <int CTRL, int RMASK>
__device__ __forceinline__ void aff_step(float& A, float& B) {
  float Ae = __int_as_float(__builtin_amdgcn_update_dpp(
      __float_as_int(1.0f), __float_as_int(A), CTRL, RMASK, 0xf, false));
  float Be = __int_as_float(__builtin_amdgcn_update_dpp(
      0, __float_as_int(B), CTRL, RMASK, 0xf, false));
  B = fmaf(A, Be, B);
  A = A * Ae;
}

// One wave per batch element; lane i owns columns [8i, 8i+8).
// Structure as R11 (current-row linear-guess branch prediction -> affine
// pieces -> depth-3 composition tree -> wave affine scan -> entries ->
// parallel true-branch outputs; distance-4 register prefetch).
// NEW: rows < 448 use a FAST body with the entire mfm/L-branch path deleted.
// Justification: mfm[k] (unclaimed future mass after col k) >= ~60 for
// m < 448 with this input (frontier advances ~1 col/row), while u <= 1.05,
// so g = max(c1*u - c1*mfm, 0) == 0 exactly -- the fast path is
// bit-identical, just skips computing provably-zero terms (PS scan, fu,
// suf tree, mfm, nc1m, g). Rows >= 448 run the full R11 body; a one-time
// bridge rebuilds fu/S/suf at the transition.
__global__ __launch_bounds__(64, 1)
void sb_kernel(const float* __restrict__ x, const float* __restrict__ xm,
               float* __restrict__ out) {
  const int lane = threadIdx.x;
  const size_t base = (size_t)blockIdx.x * NDIM * NDIM + lane * 8;
  const float* xb = x + base;
  const float* mb = xm + base;
  float* ob = out + base;

  float w8[8], fu[8], t8[8], pre[8], suf[8];
  float S, sa;
  float c1c[8], c2c[8], oc2[8];

  // 4 prefetch slots, one row each
  float4 x0[2], m0[2], x1[2], m1[2], x2[2], m2[2], x3[2], m3[2];
  x0[0] = *(const float4*)(xb);
  x0[1] = *(const float4*)(xb + 4);
  m0[0] = *(const float4*)(mb);
  m0[1] = *(const float4*)(mb + 4);
  x1[0] = *(const float4*)(xb + NDIM);
  x1[1] = *(const float4*)(xb + NDIM + 4);
  m1[0] = *(const float4*)(mb + NDIM);
  m1[1] = *(const float4*)(mb + NDIM + 4);
  x2[0] = *(const float4*)(xb + 2 * NDIM);
  x2[1] = *(const float4*)(xb + 2 * NDIM + 4);
  m2[0] = *(const float4*)(mb + 2 * NDIM);
  m2[1] = *(const float4*)(mb + 2 * NDIM + 4);
  x3[0] = *(const float4*)(xb + 3 * NDIM);
  x3[1] = *(const float4*)(xb + 3 * NDIM + 4);
  m3[0] = *(const float4*)(mb + 3 * NDIM);
  m3[1] = *(const float4*)(mb + 3 * NDIM + 4);

  // build pre tree + sa from t8 (always needed)
  auto build_pre = [&]() {
    float q01 = t8[0] + t8[1], q23 = t8[2] + t8[3], q45 = t8[4] + t8[5];
    pre[0] = 0.0f;
    pre[1] = t8[0];
    pre[2] = q01;
    pre[3] = q01 + t8[2];
    pre[4] = q01 + q23;
    pre[5] = pre[4] + t8[4];
    pre[6] = pre[4] + q45;
    pre[7] = pre[6] + t8[6];
    sa = pre[7] + t8[7];
  };
  // build suf tree + S from fu (full path only)
  auto build_suf = [&]() {
    float r23 = fu[2] + fu[3], r45 = fu[4] + fu[5], r67 = fu[6] + fu[7];
    float r4567 = r45 + r67;
    suf[7] = 0.0f;
    suf[6] = fu[7];
    suf[5] = r67;
    suf[4] = fu[5] + r67;
    suf[3] = r4567;
    suf[2] = fu[3] + r4567;
    suf[1] = r23 + r4567;
    suf[0] = fu[1] + suf[1];
    S = ((fu[0] + fu[1]) + r23) + r4567;
  };

  {  // row-0 prep: constants + scan inputs (w == 1, cs == 0)
    float xr[8] = {x0[0].x, x0[0].y, x0[0].z, x0[0].w,
                   x0[1].x, x0[1].y, x0[1].z, x0[1].w};
    float mr[8] = {m0[0].x, m0[0].y, m0[0].z, m0[0].w,
                   m0[1].x, m0[1].y, m0[1].z, m0[1].w};
#pragma unroll
    for (int k = 0; k < 8; ++k) {
      float bb = __builtin_amdgcn_rcpf(1.0f + __expf(-xr[k]));
      c2c[k] = mr[k] * bb;
      c1c[k] = mr[k] - c2c[k];
      oc2[k] = 1.0f - c2c[k];
      w8[k] = 1.0f;
      t8[k] = c2c[k];
    }
    build_pre();
  }

  // W*: slot to overwrite with row m+4; R*: slot holding row m+1.
  auto row_body = [&](auto FASTC, int m, float4 (&WX)[2], float4 (&WM)[2],
                      const float4 (&RX)[2], const float4 (&RM)[2]) {
    constexpr bool FAST = decltype(FASTC)::value;
    const int nr = (m + 4 < NDIM) ? m + 4 : NDIM - 1;
    const size_t nro = (size_t)nr * NDIM;
    WX[0] = *(const float4*)(xb + nro);
    WX[1] = *(const float4*)(xb + nro + 4);
    WM[0] = *(const float4*)(mb + nro);
    WM[1] = *(const float4*)(mb + nro + 4);

    // ---- chain head: DPP prefix scans ----
    float mfm[8], nc1m[8];
    float R_ = 0.0f;
    if constexpr (!FAST) {
      float PS = prefix_inc(S);
      float T =
          __int_as_float(__builtin_amdgcn_readlane(__float_as_int(PS), 63));
      R_ = T - PS;  // future mass strictly after this lane
    }
    float PA = prefix_inc(sa);
    float uin = fmaxf(1.0f - (PA - sa), 0.0f);  // linear entry guess
    if constexpr (!FAST) {
#pragma unroll
      for (int k = 0; k < 8; ++k) {
        mfm[k] = R_ + suf[k];
        nc1m[k] = -c1c[k] * mfm[k];
      }
    }

    // ---- parallel branch prediction at current-row linear guesses ----
    float aP[8], bP[8];
#pragma unroll
    for (int k = 0; k < 8; ++k) {
      float ug = uin - pre[k];
      bool pW = w8[k] < ug;  // U = w  (else U = u)
      if constexpr (FAST) {
        aP[k] = pW ? 1.0f : oc2[k];
        bP[k] = pW ? (-t8[k]) : 0.0f;
      } else {
        bool pL = ug > mfm[k];  // L-branch active
        float a = pW ? 1.0f : oc2[k];
        aP[k] = pL ? (a - c1c[k]) : a;
        float b0 = pW ? (-t8[k]) : 0.0f;
        bP[k] = pL ? (b0 - nc1m[k]) : b0;
      }
    }

    // ---- depth-3 composition tree (intermediates reused below) ----
    float a01 = aP[1] * aP[0], b01 = fmaf(aP[1], bP[0], bP[1]);
    float a23 = aP[3] * aP[2], b23 = fmaf(aP[3], bP[2], bP[3]);
    float a45 = aP[5] * aP[4], b45 = fmaf(aP[5], bP[4], bP[5]);
    float a67 = aP[7] * aP[6], b67 = fmaf(aP[7], bP[6], bP[7]);
    float a03 = a23 * a01, b03 = fmaf(a23, b01, b23);
    float a47 = a67 * a45, b47 = fmaf(a67, b45, b67);
    float A = a47 * a03, Bv = fmaf(a47, b03, b47);

    // ---- affine-composition wave scan + exclusive entry ----
    aff_step<0x111, 0xf>(A, Bv);
    aff_step<0x112, 0xf>(A, Bv);
    aff_step<0x114, 0xf>(A, Bv);
    aff_step<0x118, 0xf>(A, Bv);
    aff_step<0x142, 0xa>(A, Bv);
    aff_step<0x143, 0xc>(A, Bv);
    float Aex = wave_shr1(A, 1.0f);
    float Bex = wave_shr1(Bv, 0.0f);
    float e = fminf(fmaxf(Aex + Bex, 0.0f), 1.0f);

    // ---- row m+1 x-only prep (data loaded 3+ rows ago; off-chain) ----
    float c1n[8], c2n[8], oc2n[8], omn[8];
    {
      float xr[8] = {RX[0].x, RX[0].y, RX[0].z, RX[0].w,
                     RX[1].x, RX[1].y, RX[1].z, RX[1].w};
      float mr[8] = {RM[0].x, RM[0].y, RM[0].z, RM[0].w,
                     RM[1].x, RM[1].y, RM[1].z, RM[1].w};
#pragma unroll
      for (int k = 0; k < 8; ++k) {
        float bb = __builtin_amdgcn_rcpf(1.0f + __expf(-xr[k]));
        c2n[k] = mr[k] * bb;
        c1n[k] = mr[k] - c2n[k];
        oc2n[k] = 1.0f - c2n[k];
        omn[k] = 1.0f - mr[k];
      }
    }

    // ---- within-lane entries from composition-tree intermediates ----
    float uu[8];
    uu[0] = e;
    uu[1] = fmaf(aP[0], e, bP[0]);
    uu[2] = fmaf(a01, e, b01);
    uu[4] = fmaf(a03, e, b03);
    uu[3] = fmaf(aP[2], uu[2], bP[2]);
    uu[6] = fmaf(a45, uu[4], b45);
    uu[5] = fmaf(aP[4], uu[4], bP[4]);
    uu[7] = fmaf(aP[6], uu[6], bP[6]);
#pragma unroll
    for (int k = 0; k < 8; ++k) uu[k] = fmaxf(uu[k], 0.0f);

    // ---- TRUE-branch outputs, all columns in parallel ----
    float pv[8];
#pragma unroll
    for (int k = 0; k < 8; ++k) {
      float U = fminf(uu[k], w8[k]);
      float p;
      if constexpr (FAST) {
        p = c2c[k] * U;  // g == 0 provably on fast rows
      } else {
        float g = fmaxf(fmaf(c1c[k], uu[k], nc1m[k]), 0.0f);
        p = fmaf(c2c[k], U, g);
      }
      pv[k] = p;
      w8[k] -= p;
    }
    float* orow = ob + (size_t)m * NDIM;
    *(float4*)(orow) = make_float4(pv[0], pv[1], pv[2], pv[3]);
    *(float4*)(orow + 4) = make_float4(pv[4], pv[5], pv[6], pv[7]);

    // ---- next row's scan inputs + trees (the real cross-row chain) ----
#pragma unroll
    for (int k = 0; k < 8; ++k) t8[k] = c2n[k] * w8[k];
    build_pre();
    if constexpr (!FAST) {
#pragma unroll
      for (int k = 0; k < 8; ++k) fu[k] = fmaxf(w8[k] - omn[k], 0.0f);
      build_suf();
    }

#pragma unroll
    for (int k = 0; k < 8; ++k) {
      c1c[k] = c1n[k];
      c2c[k] = c2n[k];
      oc2[k] = oc2n[k];
    }
  };

  using FastT = std::integral_constant<bool, true>;
  using FullT = std::integral_constant<bool, false>;

#pragma unroll 1
  for (int m = 0; m < 448; m += 4) {
    row_body(FastT{}, m + 0, x0, m0, x1, m1);
    row_body(FastT{}, m + 1, x1, m1, x2, m2);
    row_body(FastT{}, m + 2, x2, m2, x3, m3);
    row_body(FastT{}, m + 3, x3, m3, x0, m0);
  }

  // bridge: rebuild fu/S/suf for row 448 (mask from current constants:
  // om = 1 - mask = 1 - (c1 + c2))
  {
#pragma unroll
    for (int k = 0; k < 8; ++k) {
      float om = 1.0f - c1c[k] - c2c[k];
      fu[k] = fmaxf(w8[k] - om, 0.0f);
    }
    build_suf();
  }

#pragma unroll 1
  for (int m = 448; m < NDIM; m += 4) {
    row_body(FullT{}, m + 0, x0, m0, x1, m1);
    row_body(FullT{}, m + 1, x1, m1, x2, m2);
    row_body(FullT{}, m + 2, x2, m2, x3, m3);
    row_body(FullT{}, m + 3, x3, m3, x0, m0);
  }
}

extern "C" void kernel_launch(void* const* d_in, const int* in_sizes, int n_in,
                              void* d_out, int out_size, void* d_ws, size_t ws_size,
                              hipStream_t stream) {
  const float* x = (const float*)d_in[0];
  const float* xmask = (const float*)d_in[1];
  float* out = (float*)d_out;
  (void)in_sizes; (void)n_in; (void)out_size; (void)d_ws; (void)ws_size;
  hipLaunchKernelGGL(sb_kernel, dim3(NBATCH), dim3(64), 0, stream, x, xmask, out);
}

// Round 13
// 343.408 us; speedup vs baseline: 1.7289x; 1.0266x over previous
//
#include <hip/hip_runtime.h>
#include <type_traits>

#define NBATCH 32
#define NDIM 512

// ---- DPP cross-lane primitives (VALU-speed; no LDS, no barriers) ----

template <int CTRL, int RMASK>
__device__ __forceinline__ float dpp_add(float x) {
  int t = __builtin_amdgcn_update_dpp(0, __float_as_int(x), CTRL, RMASK, 0xf,
                                      false);
  return x + __int_as_float(t);
}

// wave64 inclusive prefix sum
__device__ __forceinline__ float prefix_inc(float x) {
  x = dpp_add<0x111, 0xf>(x);  // row_shr:1
  x = dpp_add<0x112, 0xf>(x);  // row_shr:2
  x = dpp_add<0x114, 0xf>(x);  // row_shr:4
  x = dpp_add<0x118, 0xf>(x);  // row_shr:8
  x = dpp_add<0x142, 0xa>(x);  // row_bcast:15 -> rows 1,3
  x = dpp_add<0x143, 0xc>(x);  // row_bcast:31 -> rows 2,3
  return x;
}

// shift one lane up (lane i gets lane i-1); lane 0 receives `fill`
__device__ __forceinline__ float wave_shr1(float x, float fill) {
  return __int_as_float(__builtin_amdgcn_update_dpp(
      __float_as_int(fill), __float_as_int(x), 0x138 /*wave_shr:1*/, 0xf, 0xf,
      false));
}

// one step of the wave64 inclusive affine-composition scan.
// Compose earlier-then-later: B = A*Be + B ; A = A*Ae. Identity = (1,0).
template <int CTRL, int RMASK>
__device__ __forceinline__ void aff_step(float& A, float& B) {
  float Ae = __int_as_float(__builtin_amdgcn_update_dpp(
      __float_as_int(1.0f), __float_as_int(A), CTRL, RMASK, 0xf, false));
  float Be = __int_as_float(__builtin_amdgcn_update_dpp(
      0, __float_as_int(B), CTRL, RMASK, 0xf, false));
  B = fmaf(A, Be, B);
  A = A * Ae;
}

// One wave per batch element; lane i owns columns [8i, 8i+8).
// Structure as R12 (fast rows < 448 with the provably-zero mfm/L path
// deleted; current-row linear-guess branch prediction; affine pieces ->
// depth-3 composition tree -> wave affine scan -> entries -> parallel
// exact outputs p = c2*min(u,w); distance-4 register prefetch).
// R13 trims: (1) fast prep no longer computes c1/om (unused on fast rows;
// last fast group keeps c1 for the bridge); (2) comparisons hoisted:
// wp = w8+pre and sp = suf+pre are built in the off-chain tail so the
// post-scan critical region does fewer serial ops; (3) cheap wrap instead
// of clamp for the prefetch row index (wrapped data provably unused).
// MODE: 0 = fast, 1 = fast+c1 (last fast group), 2 = full.
__global__ __launch_bounds__(64, 1)
void sb_kernel(const float* __restrict__ x, const float* __restrict__ xm,
               float* __restrict__ out) {
  const int lane = threadIdx.x;
  const size_t base = (size_t)blockIdx.x * NDIM * NDIM + lane * 8;
  const float* xb = x + base;
  const float* mb = xm + base;
  float* ob = out + base;

  float w8[8], fu[8], t8[8], pre[8], suf[8], wp[8], sp[8];
  float S, sa;
  float c1c[8], c2c[8], oc2[8];

  // 4 prefetch slots, one row each
  float4 x0[2], m0[2], x1[2], m1[2], x2[2], m2[2], x3[2], m3[2];
  x0[0] = *(const float4*)(xb);
  x0[1] = *(const float4*)(xb + 4);
  m0[0] = *(const float4*)(mb);
  m0[1] = *(const float4*)(mb + 4);
  x1[0] = *(const float4*)(xb + NDIM);
  x1[1] = *(const float4*)(xb + NDIM + 4);
  m1[0] = *(const float4*)(mb + NDIM);
  m1[1] = *(const float4*)(mb + NDIM + 4);
  x2[0] = *(const float4*)(xb + 2 * NDIM);
  x2[1] = *(const float4*)(xb + 2 * NDIM + 4);
  m2[0] = *(const float4*)(mb + 2 * NDIM);
  m2[1] = *(const float4*)(mb + 2 * NDIM + 4);
  x3[0] = *(const float4*)(xb + 3 * NDIM);
  x3[1] = *(const float4*)(xb + 3 * NDIM + 4);
  m3[0] = *(const float4*)(mb + 3 * NDIM);
  m3[1] = *(const float4*)(mb + 3 * NDIM + 4);

  // build pre tree + sa from t8, then wp = w8 + pre (always needed)
  auto build_pre = [&]() {
    float q01 = t8[0] + t8[1], q23 = t8[2] + t8[3], q45 = t8[4] + t8[5];
    pre[0] = 0.0f;
    pre[1] = t8[0];
    pre[2] = q01;
    pre[3] = q01 + t8[2];
    pre[4] = q01 + q23;
    pre[5] = pre[4] + t8[4];
    pre[6] = pre[4] + q45;
    pre[7] = pre[6] + t8[6];
    sa = pre[7] + t8[7];
#pragma unroll
    for (int k = 0; k < 8; ++k) wp[k] = w8[k] + pre[k];
  };
  // build suf tree + S from fu, then sp = suf + pre (full path only)
  auto build_suf = [&]() {
    float r23 = fu[2] + fu[3], r45 = fu[4] + fu[5], r67 = fu[6] + fu[7];
    float r4567 = r45 + r67;
    suf[7] = 0.0f;
    suf[6] = fu[7];
    suf[5] = r67;
    suf[4] = fu[5] + r67;
    suf[3] = r4567;
    suf[2] = fu[3] + r4567;
    suf[1] = r23 + r4567;
    suf[0] = fu[1] + suf[1];
    S = ((fu[0] + fu[1]) + r23) + r4567;
#pragma unroll
    for (int k = 0; k < 8; ++k) sp[k] = suf[k] + pre[k];
  };

  {  // row-0 prep: constants + scan inputs (w == 1, cs == 0)
    float xr[8] = {x0[0].x, x0[0].y, x0[0].z, x0[0].w,
                   x0[1].x, x0[1].y, x0[1].z, x0[1].w};
    float mr[8] = {m0[0].x, m0[0].y, m0[0].z, m0[0].w,
                   m0[1].x, m0[1].y, m0[1].z, m0[1].w};
#pragma unroll
    for (int k = 0; k < 8; ++k) {
      float bb = __builtin_amdgcn_rcpf(1.0f + __expf(-xr[k]));
      c2c[k] = mr[k] * bb;
      oc2[k] = 1.0f - c2c[k];
      w8[k] = 1.0f;
      t8[k] = c2c[k];
    }
    build_pre();
  }

  // W*: slot to overwrite with row m+4; R*: slot holding row m+1.
  auto row_body = [&](auto MODEC, int m, float4 (&WX)[2], float4 (&WM)[2],
                      const float4 (&RX)[2], const float4 (&RM)[2]) {
    constexpr int MODE = decltype(MODEC)::value;
    constexpr bool FAST = (MODE < 2);
    const size_t nro = (size_t)((m + 4) & (NDIM - 1)) * NDIM;
    WX[0] = *(const float4*)(xb + nro);
    WX[1] = *(const float4*)(xb + nro + 4);
    WM[0] = *(const float4*)(mb + nro);
    WM[1] = *(const float4*)(mb + nro + 4);

    // ---- chain head: DPP prefix scans ----
    float mfm[8], nc1m[8];
    float R_ = 0.0f;
    if constexpr (!FAST) {
      float PS = prefix_inc(S);
      float T =
          __int_as_float(__builtin_amdgcn_readlane(__float_as_int(PS), 63));
      R_ = T - PS;  // future mass strictly after this lane
    }
    float PA = prefix_inc(sa);
    float uin = fmaxf(1.0f - (PA - sa), 0.0f);  // linear entry guess
    if constexpr (!FAST) {
#pragma unroll
      for (int k = 0; k < 8; ++k) {
        mfm[k] = R_ + suf[k];
        nc1m[k] = -c1c[k] * mfm[k];
      }
    }

    // ---- parallel branch prediction (hoisted comparisons) ----
    float aP[8], bP[8];
    if constexpr (FAST) {
#pragma unroll
      for (int k = 0; k < 8; ++k) {
        bool pW = wp[k] < uin;  // w8 < uin - pre
        aP[k] = pW ? 1.0f : oc2[k];
        bP[k] = pW ? (-t8[k]) : 0.0f;
      }
    } else {
      float d = uin - R_;
#pragma unroll
      for (int k = 0; k < 8; ++k) {
        bool pW = wp[k] < uin;
        bool pL = d > sp[k];  // uin - pre > mfm
        float a = pW ? 1.0f : oc2[k];
        aP[k] = pL ? (a - c1c[k]) : a;
        float b0 = pW ? (-t8[k]) : 0.0f;
        bP[k] = pL ? (b0 - nc1m[k]) : b0;
      }
    }

    // ---- depth-3 composition tree (intermediates reused below) ----
    float a01 = aP[1] * aP[0], b01 = fmaf(aP[1], bP[0], bP[1]);
    float a23 = aP[3] * aP[2], b23 = fmaf(aP[3], bP[2], bP[3]);
    float a45 = aP[5] * aP[4], b45 = fmaf(aP[5], bP[4], bP[5]);
    float a67 = aP[7] * aP[6], b67 = fmaf(aP[7], bP[6], bP[7]);
    float a03 = a23 * a01, b03 = fmaf(a23, b01, b23);
    float a47 = a67 * a45, b47 = fmaf(a67, b45, b67);
    float A = a47 * a03, Bv = fmaf(a47, b03, b47);

    // ---- affine-composition wave scan + exclusive entry ----
    aff_step<0x111, 0xf>(A, Bv);
    aff_step<0x112, 0xf>(A, Bv);
    aff_step<0x114, 0xf>(A, Bv);
    aff_step<0x118, 0xf>(A, Bv);
    aff_step<0x142, 0xa>(A, Bv);
    aff_step<0x143, 0xc>(A, Bv);
    float Aex = wave_shr1(A, 1.0f);
    float Bex = wave_shr1(Bv, 0.0f);
    float e = fminf(fmaxf(Aex + Bex, 0.0f), 1.0f);

    // ---- row m+1 x-only prep (data loaded 3+ rows ago; off-chain) ----
    float c1n[8], c2n[8], oc2n[8], omn[8];
    {
      float xr[8] = {RX[0].x, RX[0].y, RX[0].z, RX[0].w,
                     RX[1].x, RX[1].y, RX[1].z, RX[1].w};
      float mr[8] = {RM[0].x, RM[0].y, RM[0].z, RM[0].w,
                     RM[1].x, RM[1].y, RM[1].z, RM[1].w};
#pragma unroll
      for (int k = 0; k < 8; ++k) {
        float bb = __builtin_amdgcn_rcpf(1.0f + __expf(-xr[k]));
        c2n[k] = mr[k] * bb;
        oc2n[k] = 1.0f - c2n[k];
        if constexpr (MODE >= 1) c1n[k] = mr[k] - c2n[k];
        if constexpr (MODE == 2) omn[k] = 1.0f - mr[k];
      }
    }

    // ---- within-lane entries from composition-tree intermediates ----
    float uu[8];
    uu[0] = e;
    uu[1] = fmaf(aP[0], e, bP[0]);
    uu[2] = fmaf(a01, e, b01);
    uu[4] = fmaf(a03, e, b03);
    uu[3] = fmaf(aP[2], uu[2], bP[2]);
    uu[6] = fmaf(a45, uu[4], b45);
    uu[5] = fmaf(aP[4], uu[4], bP[4]);
    uu[7] = fmaf(aP[6], uu[6], bP[6]);
#pragma unroll
    for (int k = 0; k < 8; ++k) uu[k] = fmaxf(uu[k], 0.0f);

    // ---- TRUE-branch outputs, all columns in parallel ----
    float pv[8];
#pragma unroll
    for (int k = 0; k < 8; ++k) {
      float U = fminf(uu[k], w8[k]);
      float p;
      if constexpr (FAST) {
        p = c2c[k] * U;  // g == 0 provably on fast rows
      } else {
        float g = fmaxf(fmaf(c1c[k], uu[k], nc1m[k]), 0.0f);
        p = fmaf(c2c[k], U, g);
      }
      pv[k] = p;
      w8[k] -= p;
    }
    float* orow = ob + (size_t)m * NDIM;
    *(float4*)(orow) = make_float4(pv[0], pv[1], pv[2], pv[3]);
    *(float4*)(orow + 4) = make_float4(pv[4], pv[5], pv[6], pv[7]);

    // ---- next row's scan inputs + trees (the real cross-row chain) ----
#pragma unroll
    for (int k = 0; k < 8; ++k) t8[k] = c2n[k] * w8[k];
    build_pre();
    if constexpr (MODE == 2) {
#pragma unroll
      for (int k = 0; k < 8; ++k) fu[k] = fmaxf(w8[k] - omn[k], 0.0f);
      build_suf();
    }

#pragma unroll
    for (int k = 0; k < 8; ++k) {
      c2c[k] = c2n[k];
      oc2[k] = oc2n[k];
      if constexpr (MODE >= 1) c1c[k] = c1n[k];
    }
  };

  using Fast0 = std::integral_constant<int, 0>;
  using Fast1 = std::integral_constant<int, 1>;
  using Full2 = std::integral_constant<int, 2>;

#pragma unroll 1
  for (int m = 0; m < 444; m += 4) {
    row_body(Fast0{}, m + 0, x0, m0, x1, m1);
    row_body(Fast0{}, m + 1, x1, m1, x2, m2);
    row_body(Fast0{}, m + 2, x2, m2, x3, m3);
    row_body(Fast0{}, m + 3, x3, m3, x0, m0);
  }
  // last fast group: also carries c1 forward for the bridge
  row_body(Fast1{}, 444, x0, m0, x1, m1);
  row_body(Fast1{}, 445, x1, m1, x2, m2);
  row_body(Fast1{}, 446, x2, m2, x3, m3);
  row_body(Fast1{}, 447, x3, m3, x0, m0);

  // bridge: rebuild fu/S/suf/sp for row 448 (om = 1 - mask = 1 - (c1+c2))
  {
#pragma unroll
    for (int k = 0; k < 8; ++k) {
      float om = 1.0f - c1c[k] - c2c[k];
      fu[k] = fmaxf(w8[k] - om, 0.0f);
    }
    build_suf();
  }

#pragma unroll 1
  for (int m = 448; m < NDIM; m += 4) {
    row_body(Full2{}, m + 0, x0, m0, x1, m1);
    row_body(Full2{}, m + 1, x1, m1, x2, m2);
    row_body(Full2{}, m + 2, x2, m2, x3, m3);
    row_body(Full2{}, m + 3, x3, m3, x0, m0);
  }
}

extern "C" void kernel_launch(void* const* d_in, const int* in_sizes, int n_in,
                              void* d_out, int out_size, void* d_ws, size_t ws_size,
                              hipStream_t stream) {
  const float* x = (const float*)d_in[0];
  const float* xmask = (const float*)d_in[1];
  float* out = (float*)d_out;
  (void)in_sizes; (void)n_in; (void)out_size; (void)d_ws; (void)ws_size;
  hipLaunchKernelGGL(sb_kernel, dim3(NBATCH), dim3(64), 0, stream, x, xmask, out);
}